// Round 8
// baseline (391.450 us; speedup 1.0000x reference)
//
#include <hip/hip_runtime.h>
#include <hip/hip_bf16.h>

// ---------------------------------------------------------------------------
// VisualContrastAttention on MI355X (gfx950)
// B=32, N=1024 (32x32), C=768, heads=12, hd=64, pool 8x8=64 tokens
// Pipeline:
//   K0  merged cast x/Wqkv/Wproj f32->bf16 (one launch)
//   K1  qkv GEMM: 256x256, 8-wave, 8-phase counted-vmcnt (T1+T2+T3/T4+T5)
//   K2a gq reduction + Wpos/Wneg embeddings -> ep/en
//   K2b depthwise conv3x3+GELU+avgpool -> t_pos/t_neg (bf16)
//   K3  stage-1 flash attn: gload_lds dbuf KV staging (XOR swizzle),
//       t-fragments reg-direct; writes v_contrast bf16 vct[bh][d][m]
//   K4  stage-2: 4x-wide blocks (256 q rows), tp/tn/Vc staged once
//   K5  proj GEMM: 128x256, 8-wave, 2-phase counted-vmcnt + bias -> f32
// ---------------------------------------------------------------------------

typedef __attribute__((ext_vector_type(8))) short short8;
typedef __attribute__((ext_vector_type(4))) short bf16x4;
typedef __attribute__((ext_vector_type(4))) float f32x4;

#define DEV static __device__ __forceinline__

DEV unsigned short f2bf(float f) {
  unsigned int b; __builtin_memcpy(&b, &f, 4);
  unsigned int r = (b + 0x7FFFu + ((b >> 16) & 1u)) >> 16;
  return (unsigned short)r;
}
DEV float bf2f(unsigned short u) {
  unsigned int b = ((unsigned int)u) << 16;
  float f; __builtin_memcpy(&f, &b, 4);
  return f;
}

DEV void gload16(const unsigned short* g, unsigned short* l) {
  __builtin_amdgcn_global_load_lds(
      (const __attribute__((address_space(1))) unsigned int*)g,
      (__attribute__((address_space(3))) unsigned int*)l, 16, 0, 0);
}

DEV void bar() {
  asm volatile("" ::: "memory");
  __builtin_amdgcn_s_barrier();
  asm volatile("" ::: "memory");
}
DEV void wait_vm4() { asm volatile("s_waitcnt vmcnt(4)" ::: "memory"); __builtin_amdgcn_sched_barrier(0); }
DEV void wait_vm0() { asm volatile("s_waitcnt vmcnt(0)" ::: "memory"); __builtin_amdgcn_sched_barrier(0); }
DEV void wait_lgkm0() { asm volatile("s_waitcnt lgkmcnt(0)" ::: "memory"); __builtin_amdgcn_sched_barrier(0); }

// ---- workspace layout (bytes) ---------------------------------------------
constexpr size_t SZ_QKV = (size_t)32 * 12 * 1024 * 64 * 2;   // 50331648 bf16
constexpr size_t OFF_Q   = 0;
constexpr size_t OFF_K   = OFF_Q + SZ_QKV;
constexpr size_t OFF_VT  = OFF_K + SZ_QKV;                    // vt[bh][d][n] bf16
constexpr size_t OFF_TPB = OFF_VT + SZ_QKV;                   // bf16 384*64*64
constexpr size_t OFF_TNB = OFF_TPB + 3145728;
constexpr size_t OFF_VCT = OFF_TNB + 3145728;                 // bf16 vct[bh][d][m]
constexpr size_t OFF_OP  = OFF_VCT + 6291456;                 // bf16 32768*768
constexpr size_t OFF_XB  = OFF_OP + SZ_QKV;
constexpr size_t OFF_WQ  = OFF_XB + SZ_QKV;
constexpr size_t OFF_WP  = OFF_WQ + 3538944;
constexpr size_t OFF_EP  = OFF_WP + 1179648;                  // f32 384*64
constexpr size_t OFF_EN  = OFF_EP + 98304;

// ---- K0: merged f32 -> bf16 cast (x, Wqkv, Wproj) -------------------------
__global__ __launch_bounds__(256) void cast3_kernel(const float* __restrict__ x,
    const float* __restrict__ wq, const float* __restrict__ wp,
    unsigned short* __restrict__ xd, unsigned short* __restrict__ wqd,
    unsigned short* __restrict__ wpd) {
  const int i = blockIdx.x * 256 + threadIdx.x;    // float4 index
  const float* src; unsigned short* dst; int off;
  if (i < 6291456) { src = x; dst = xd; off = i; }
  else if (i < 6733824) { src = wq; dst = wqd; off = i - 6291456; }
  else { src = wp; dst = wpd; off = i - 6733824; }
  float4 v = reinterpret_cast<const float4*>(src)[off];
  ushort4 o;
  o.x = f2bf(v.x); o.y = f2bf(v.y); o.z = f2bf(v.z); o.w = f2bf(v.w);
  reinterpret_cast<ushort4*>(dst)[off] = o;
}

// stage 128 rows x 64 cols (stride-768 source) with XOR-swizzled source chunks
DEV void stage_ht(const unsigned short* __restrict__ G, unsigned short* shbase,
                  int grow0, int k0, int htrow0, int w, int lane) {
  const int rl = lane >> 3;
  const int ck = (lane & 7) ^ rl;
  const unsigned short* s0 = G + (size_t)(grow0 + htrow0 + w * 16 + rl) * 768 + k0 + ck * 8;
  gload16(s0, shbase + (htrow0 + w * 16) * 64);
  gload16(s0 + (size_t)8 * 768, shbase + (htrow0 + w * 16 + 8) * 64);
}

// ---- K1: qkv GEMM, 256^2 8-phase (verified rounds 5-7) --------------------
__global__ __launch_bounds__(512, 2) void gemm_qkv_kernel(const unsigned short* __restrict__ A,
    const unsigned short* __restrict__ Bm, unsigned short* __restrict__ q,
    unsigned short* __restrict__ k, unsigned short* __restrict__ vt) {
  __shared__ __align__(16) unsigned short sh[65536];   // 128 KiB
  const int t = threadIdx.x;
  const int lane = t & 63;
  const int w = t >> 6;
  const int wm = w >> 2, wn = w & 3;
  const int l = lane & 15, g = lane >> 4;
  const int id = blockIdx.x;
  const int swz = (id & 7) * 144 + (id >> 3);
  const int rt = swz / 9, ct = swz % 9;
  const int row0 = rt * 256, col0 = ct * 256;

  f32x4 acc[8][4];
#pragma unroll
  for (int i = 0; i < 8; ++i)
#pragma unroll
    for (int j = 0; j < 4; ++j) acc[i][j] = (f32x4){0.f, 0.f, 0.f, 0.f};

  stage_ht(A, sh, row0, 0, 0, w, lane);
  stage_ht(A, sh, row0, 0, 128, w, lane);
  stage_ht(Bm, sh + 32768, col0, 0, 0, w, lane);
  stage_ht(Bm, sh + 32768, col0, 0, 128, w, lane);
  stage_ht(Bm, sh + 32768 + 16384, col0, 64, 0, w, lane);
  stage_ht(Bm, sh + 32768 + 16384, col0, 64, 128, w, lane);
  wait_vm4();
  bar();

  for (int m = 0; m < 12; ++m) {
    const int d = m & 1;
    const unsigned short* Ab = sh + d * 16384;
    const unsigned short* Bb = sh + 32768 + d * 16384;
    short8 af[4][2], bf0[2][2], bf1[2][2];
    // p1
#pragma unroll
    for (int mt = 0; mt < 4; ++mt)
#pragma unroll
      for (int kc = 0; kc < 2; ++kc) {
        const int r = wm * 128 + mt * 16 + l;
        af[mt][kc] = *reinterpret_cast<const short8*>(Ab + r * 64 + (((kc << 2) | g) ^ (r & 7)) * 8);
      }
#pragma unroll
    for (int nt = 0; nt < 2; ++nt)
#pragma unroll
      for (int kc = 0; kc < 2; ++kc) {
        const int r = wn * 64 + nt * 16 + l;
        bf0[nt][kc] = *reinterpret_cast<const short8*>(Bb + r * 64 + (((kc << 2) | g) ^ (r & 7)) * 8);
      }
    if (m + 1 < 12) stage_ht(A, sh + (d ^ 1) * 16384, row0, (m + 1) * 64, 0, w, lane);
    bar();
    __builtin_amdgcn_s_setprio(1);
#pragma unroll
    for (int kc = 0; kc < 2; ++kc)
#pragma unroll
      for (int mt = 0; mt < 4; ++mt)
#pragma unroll
        for (int nt = 0; nt < 2; ++nt)
          acc[mt][nt] = __builtin_amdgcn_mfma_f32_16x16x32_bf16(af[mt][kc], bf0[nt][kc], acc[mt][nt], 0, 0, 0);
    __builtin_amdgcn_s_setprio(0);
    bar();
    // p2
#pragma unroll
    for (int nt = 0; nt < 2; ++nt)
#pragma unroll
      for (int kc = 0; kc < 2; ++kc) {
        const int r = wn * 64 + 32 + nt * 16 + l;
        bf1[nt][kc] = *reinterpret_cast<const short8*>(Bb + r * 64 + (((kc << 2) | g) ^ (r & 7)) * 8);
      }
    if (m + 1 < 12) stage_ht(A, sh + (d ^ 1) * 16384, row0, (m + 1) * 64, 128, w, lane);
    bar();
    __builtin_amdgcn_s_setprio(1);
#pragma unroll
    for (int kc = 0; kc < 2; ++kc)
#pragma unroll
      for (int mt = 0; mt < 4; ++mt)
#pragma unroll
        for (int nt = 0; nt < 2; ++nt)
          acc[mt][2 + nt] = __builtin_amdgcn_mfma_f32_16x16x32_bf16(af[mt][kc], bf1[nt][kc], acc[mt][2 + nt], 0, 0, 0);
    __builtin_amdgcn_s_setprio(0);
    bar();
    // p3
#pragma unroll
    for (int mt = 0; mt < 4; ++mt)
#pragma unroll
      for (int kc = 0; kc < 2; ++kc) {
        const int r = wm * 128 + 64 + mt * 16 + l;
        af[mt][kc] = *reinterpret_cast<const short8*>(Ab + r * 64 + (((kc << 2) | g) ^ (r & 7)) * 8);
      }
    if (m + 2 < 12) stage_ht(Bm, sh + 32768 + d * 16384, col0, (m + 2) * 64, 0, w, lane);
    bar();
    __builtin_amdgcn_s_setprio(1);
#pragma unroll
    for (int kc = 0; kc < 2; ++kc)
#pragma unroll
      for (int mt = 0; mt < 4; ++mt)
#pragma unroll
        for (int nt = 0; nt < 2; ++nt)
          acc[4 + mt][2 + nt] = __builtin_amdgcn_mfma_f32_16x16x32_bf16(af[mt][kc], bf1[nt][kc], acc[4 + mt][2 + nt], 0, 0, 0);
    __builtin_amdgcn_s_setprio(0);
    bar();
    // p4
    if (m + 2 < 12) stage_ht(Bm, sh + 32768 + d * 16384, col0, (m + 2) * 64, 128, w, lane);
    bar();
    __builtin_amdgcn_s_setprio(1);
#pragma unroll
    for (int kc = 0; kc < 2; ++kc)
#pragma unroll
      for (int mt = 0; mt < 4; ++mt)
#pragma unroll
        for (int nt = 0; nt < 2; ++nt)
          acc[4 + mt][nt] = __builtin_amdgcn_mfma_f32_16x16x32_bf16(af[mt][kc], bf0[nt][kc], acc[4 + mt][nt], 0, 0, 0);
    __builtin_amdgcn_s_setprio(0);
    if (m < 11) {
      if (m == 10) wait_vm0(); else wait_vm4();
    }
    bar();
  }

  const int s_ = ct / 3;
  if (s_ == 2) {
#pragma unroll
    for (int ni = 0; ni < 4; ++ni) {
      const int colg = (ct % 3) * 256 + wn * 64 + ni * 16 + l;
      const int head = colg >> 6, dd = colg & 63;
#pragma unroll
      for (int mi = 0; mi < 8; ++mi) {
        const int row = row0 + wm * 128 + mi * 16 + (g << 2);
        const int b = row >> 10, n = row & 1023;
        ushort4 pk;
        pk.x = f2bf(acc[mi][ni][0]); pk.y = f2bf(acc[mi][ni][1]);
        pk.z = f2bf(acc[mi][ni][2]); pk.w = f2bf(acc[mi][ni][3]);
        *reinterpret_cast<ushort4*>(vt + ((((size_t)b * 12 + head) * 64 + dd) << 10) + n) = pk;
      }
    }
  } else {
    unsigned short* dst = (s_ == 0) ? q : k;
#pragma unroll
    for (int ni = 0; ni < 4; ++ni) {
      const int colg = (ct % 3) * 256 + wn * 64 + ni * 16 + l;
      const int head = colg >> 6, dd = colg & 63;
#pragma unroll
      for (int mi = 0; mi < 8; ++mi) {
#pragma unroll
        for (int r = 0; r < 4; ++r) {
          const int row = row0 + wm * 128 + mi * 16 + (g << 2) + r;
          const int b = row >> 10, n = row & 1023;
          dst[(((size_t)b * 12 + head) * 1024 + n) * 64 + dd] = f2bf(acc[mi][ni][r]);
        }
      }
    }
  }
}

// ---- K2a: gq reduction + e+/e- embeddings ---------------------------------
__global__ __launch_bounds__(256) void gq_embed_kernel(const unsigned short* __restrict__ qg,
    const float* __restrict__ Wpos, const float* __restrict__ Wneg,
    float* __restrict__ ep, float* __restrict__ en) {
  const int bh = blockIdx.x;
  const unsigned short* qp = qg + (size_t)bh * 65536;
  __shared__ float red2[32][64];
  __shared__ float gq_s[64];
  const int t = threadIdx.x;
  const int c8 = (t & 7) << 3;
  const int part = t >> 3;
  float s[8] = {0.f, 0.f, 0.f, 0.f, 0.f, 0.f, 0.f, 0.f};
  for (int i = 0; i < 32; ++i) {
    const short8 v = *reinterpret_cast<const short8*>(qp + (size_t)(part * 32 + i) * 64 + c8);
#pragma unroll
    for (int j = 0; j < 8; ++j) s[j] += bf2f((unsigned short)v[j]);
  }
#pragma unroll
  for (int j = 0; j < 8; ++j) red2[part][c8 + j] = s[j];
  __syncthreads();
  if (t < 64) {
    float s2 = 0.f;
    for (int p = 0; p < 32; ++p) s2 += red2[p][t];
    gq_s[t] = s2 * (1.0f / 1024.0f);
  }
  __syncthreads();
  if (t < 128) {
    const int d2 = t & 63;
    const float* Wm = (t < 64) ? Wpos : Wneg;
    float e = 0.f;
    for (int dd = 0; dd < 64; ++dd) e += gq_s[dd] * Wm[d2 * 64 + dd];
    (t < 64 ? ep : en)[bh * 64 + d2] = e;
  }
}

// ---- K2b: conv3x3 depthwise + GELU + 4x4 mean pool -> t_pos/t_neg ---------
__global__ __launch_bounds__(256) void conv_pool_kernel(const unsigned short* __restrict__ qg,
    const float* __restrict__ conv_w, const float* __restrict__ ep,
    const float* __restrict__ en, unsigned short* __restrict__ t_pos,
    unsigned short* __restrict__ t_neg) {
  const int bh = blockIdx.x;
  const int quad = blockIdx.y;
  const unsigned short* qp = qg + (size_t)bh * 65536;
  __shared__ float pool_s[16][64];
  const int t = threadIdx.x;
  const int dg = t & 7, sp = t >> 3;
  const int d0 = dg << 3;
  float cw[3][3][8];
#pragma unroll
  for (int ky = 0; ky < 3; ++ky)
#pragma unroll
    for (int kx = 0; kx < 3; ++kx)
#pragma unroll
      for (int j = 0; j < 8; ++j)
        cw[ky][kx][j] = conv_w[(d0 + j) * 9 + ky * 3 + kx];
#pragma unroll
  for (int pyl = 0; pyl < 2; ++pyl) {
    float win[8] = {0.f, 0.f, 0.f, 0.f, 0.f, 0.f, 0.f, 0.f};
#pragma unroll
    for (int iy = 0; iy < 4; ++iy) {
      const int y = quad * 8 + pyl * 4 + iy;
      float a[8] = {0.f, 0.f, 0.f, 0.f, 0.f, 0.f, 0.f, 0.f};
#pragma unroll
      for (int ky = 0; ky < 3; ++ky) {
        const int yy = y + ky - 1;
        if (yy < 0 || yy > 31) continue;
#pragma unroll
        for (int kx = 0; kx < 3; ++kx) {
          const int xx = sp + kx - 1;
          if (xx < 0 || xx > 31) continue;
          const short8 v = *reinterpret_cast<const short8*>(qp + (size_t)(yy * 32 + xx) * 64 + d0);
#pragma unroll
          for (int j = 0; j < 8; ++j) a[j] += bf2f((unsigned short)v[j]) * cw[ky][kx][j];
        }
      }
#pragma unroll
      for (int j = 0; j < 8; ++j)
        win[j] += 0.5f * a[j] * (1.0f + erff(a[j] * 0.70710678118654752440f));
    }
#pragma unroll
    for (int j = 0; j < 8; ++j) {
      win[j] += __shfl_xor(win[j], 8);
      win[j] += __shfl_xor(win[j], 16);
    }
    if ((sp & 3) == 0) {
      const int px = sp >> 2;
#pragma unroll
      for (int j = 0; j < 8; ++j) pool_s[pyl * 8 + px][d0 + j] = win[j];
    }
  }
  __syncthreads();
#pragma unroll
  for (int i = 0; i < 4; ++i) {
    const int idx = i * 256 + t;
    const int m = idx >> 6, dd = idx & 63;
    const int mg = quad * 16 + m;
    const float base = pool_s[m][dd] * (1.0f / 16.0f);
    t_pos[(size_t)bh * 4096 + mg * 64 + dd] = f2bf(base + ep[bh * 64 + dd]);
    t_neg[(size_t)bh * 4096 + mg * 64 + dd] = f2bf(base + en[bh * 64 + dd]);
  }
}

// ---- K3: stage-1 flash attn, gload_lds dbuf staging, vct bf16 out ---------
__global__ __launch_bounds__(256) void stage1_kernel(const unsigned short* __restrict__ kg,
    const unsigned short* __restrict__ vtg, const unsigned short* __restrict__ tpb,
    const unsigned short* __restrict__ tnb, const float* __restrict__ lam1p,
    const float* __restrict__ norm1_w, unsigned short* __restrict__ vct) {
  const int bh = blockIdx.x;
  __shared__ __align__(16) unsigned short Ks[2][4096];
  __shared__ __align__(16) unsigned short Vts[2][4096];
  const int t = threadIdx.x;
  const int lane = t & 63;
  const int w = t >> 6;
  const int l = lane & 15, g = lane >> 4;
  const size_t kbase = (size_t)bh * 65536;
  const int rl = lane >> 3, ck = (lane & 7) ^ rl;

  // t fragments reg-direct (each lane reads its own 2x16B per pass; L2-hot)
  short8 tf[2][2];
#pragma unroll
  for (int h = 0; h < 2; ++h) {
    tf[0][h] = *reinterpret_cast<const short8*>(tpb + (size_t)bh * 4096 + (w * 16 + l) * 64 + h * 32 + g * 8);
    tf[1][h] = *reinterpret_cast<const short8*>(tnb + (size_t)bh * 4096 + (w * 16 + l) * 64 + h * 32 + g * 8);
  }
  auto stageKV = [&](int buf, int n0) {
    const unsigned short* ksrc = kg + kbase + (size_t)(n0 + w * 16 + rl) * 64 + ck * 8;
    gload16(ksrc, &Ks[buf][(w * 16) * 64]);
    gload16(ksrc + (size_t)8 * 64, &Ks[buf][(w * 16 + 8) * 64]);
    const unsigned short* vsrc = vtg + kbase + (size_t)(w * 16 + rl) * 1024 + n0 + ck * 8;
    gload16(vsrc, &Vts[buf][(w * 16) * 64]);
    gload16(vsrc + (size_t)8 * 1024, &Vts[buf][(w * 16 + 8) * 64]);
  };
  stageKV(0, 0);
  __syncthreads();

  float Mo[2] = {-1e30f, -1e30f}, Lo[2] = {0.f, 0.f};
  f32x4 acc[2][4];
#pragma unroll
  for (int pp = 0; pp < 2; ++pp)
#pragma unroll
    for (int dt = 0; dt < 4; ++dt) acc[pp][dt] = (f32x4){0.f, 0.f, 0.f, 0.f};

  for (int it = 0; it < 16; ++it) {
    const int buf = it & 1;
    if (it < 15) stageKV(buf ^ 1, (it + 1) * 64);
    short8 kf[4][2];
#pragma unroll
    for (int tile = 0; tile < 4; ++tile)
#pragma unroll
      for (int h = 0; h < 2; ++h) {
        const int R = tile * 16 + l;
        kf[tile][h] = *reinterpret_cast<const short8*>(&Ks[buf][R * 64 + ((((h << 2) | g)) ^ (l & 7)) * 8]);
      }
    bf16x4 pf[2][4];
#pragma unroll
    for (int pp = 0; pp < 2; ++pp) {
      f32x4 s[4];
#pragma unroll
      for (int tile = 0; tile < 4; ++tile) {
        s[tile] = (f32x4){0.f, 0.f, 0.f, 0.f};
#pragma unroll
        for (int h = 0; h < 2; ++h)
          s[tile] = __builtin_amdgcn_mfma_f32_16x16x32_bf16(kf[tile][h], tf[pp][h], s[tile], 0, 0, 0);
      }
      float p[4][4];
      float tmax = -1e30f;
#pragma unroll
      for (int tile = 0; tile < 4; ++tile)
#pragma unroll
        for (int r = 0; r < 4; ++r) {
          const float v = s[tile][r] * 0.125f;
          p[tile][r] = v;
          tmax = fmaxf(tmax, v);
        }
      tmax = fmaxf(tmax, __shfl_xor(tmax, 16));
      tmax = fmaxf(tmax, __shfl_xor(tmax, 32));
      const float nm = fmaxf(Mo[pp], tmax);
      const float al = __expf(Mo[pp] - nm);
      Mo[pp] = nm;
      float ps = 0.f;
#pragma unroll
      for (int tile = 0; tile < 4; ++tile)
#pragma unroll
        for (int r = 0; r < 4; ++r) {
          const float e = __expf(p[tile][r] - nm);
          p[tile][r] = e;
          ps += e;
        }
      ps += __shfl_xor(ps, 16);
      ps += __shfl_xor(ps, 32);
      Lo[pp] = Lo[pp] * al + ps;
#pragma unroll
      for (int tile = 0; tile < 4; ++tile) {
        bf16x4 pk;
        pk[0] = (short)f2bf(p[tile][0]); pk[1] = (short)f2bf(p[tile][1]);
        pk[2] = (short)f2bf(p[tile][2]); pk[3] = (short)f2bf(p[tile][3]);
        pf[pp][tile] = pk;
      }
      float ar[4];
#pragma unroll
      for (int r = 0; r < 4; ++r) ar[r] = __shfl(al, 4 * g + r);
#pragma unroll
      for (int dt = 0; dt < 4; ++dt)
#pragma unroll
        for (int r = 0; r < 4; ++r) acc[pp][dt][r] *= ar[r];
    }
#pragma unroll
    for (int tile = 0; tile < 4; ++tile)
#pragma unroll
      for (int dt = 0; dt < 4; ++dt) {
        const int R = dt * 16 + l;
        const bf16x4 vf = *reinterpret_cast<const bf16x4*>(
            &Vts[buf][R * 64 + (((2 * tile + (g >> 1)) ^ (l & 7)) * 8) + (g & 1) * 4]);
        acc[0][dt] = __builtin_amdgcn_mfma_f32_16x16x16bf16_1k(pf[0][tile], vf, acc[0][dt], 0, 0, 0);
        acc[1][dt] = __builtin_amdgcn_mfma_f32_16x16x16bf16_1k(pf[1][tile], vf, acc[1][dt], 0, 0, 0);
      }
    __syncthreads();
  }
  const float inv0 = 1.f / Lo[0], inv1 = 1.f / Lo[1];
  float i1r[4], i2r[4];
#pragma unroll
  for (int r = 0; r < 4; ++r) {
    i1r[r] = __shfl(inv0, 4 * g + r);
    i2r[r] = __shfl(inv1, 4 * g + r);
  }
  const float lam1 = lam1p[0];
  float od[4][4], ss[4] = {0.f, 0.f, 0.f, 0.f};
#pragma unroll
  for (int dt = 0; dt < 4; ++dt)
#pragma unroll
    for (int r = 0; r < 4; ++r) {
      const float v = acc[0][dt][r] * i1r[r] - lam1 * (acc[1][dt][r] * i2r[r]);
      od[dt][r] = v;
      ss[r] += v * v;
    }
#pragma unroll
  for (int r = 0; r < 4; ++r) {
    ss[r] += __shfl_xor(ss[r], 1);
    ss[r] += __shfl_xor(ss[r], 2);
    ss[r] += __shfl_xor(ss[r], 4);
    ss[r] += __shfl_xor(ss[r], 8);
  }
  float sc[4];
#pragma unroll
  for (int r = 0; r < 4; ++r) sc[r] = 0.5f / (sqrtf(ss[r]) * 0.125f + 1e-6f);
  const int mb = w * 16 + 4 * g;
#pragma unroll
  for (int dt = 0; dt < 4; ++dt) {
    const int dd = dt * 16 + l;
    const float nw = norm1_w[dd];
    ushort4 pk;
    pk.x = f2bf(od[dt][0] * sc[0] * nw);
    pk.y = f2bf(od[dt][1] * sc[1] * nw);
    pk.z = f2bf(od[dt][2] * sc[2] * nw);
    pk.w = f2bf(od[dt][3] * sc[3] * nw);
    *reinterpret_cast<ushort4*>(vct + (size_t)bh * 4096 + dd * 64 + mb) = pk;
  }
}

// ---- K4: stage-2, 4x-wide blocks (256 q rows each) ------------------------
// grid (384, 4); per block: stage tp/tn/Vc (once) + Qs (256 rows);
// wave w processes strips s=0..3 at rows q0 + (w*4+s)*16.
__global__ __launch_bounds__(256) void stage2_kernel(const unsigned short* __restrict__ qg,
    const unsigned short* __restrict__ tpb, const unsigned short* __restrict__ tnb,
    const unsigned short* __restrict__ vctg, const float* __restrict__ lam2p,
    const float* __restrict__ norm2_w, unsigned short* __restrict__ opb) {
  const int bh = blockIdx.x;
  const int q0 = blockIdx.y * 256;
  __shared__ unsigned short tp[64 * 72], tn[64 * 72], Vc[64 * 72];
  __shared__ unsigned short Qs[256 * 72];
  const int t = threadIdx.x;
  const int lane = t & 63;
  const int w = t >> 6;
  const int l = lane & 15, g = lane >> 4;
  for (int L = t; L < 512; L += 256) {
    const int r = L >> 3, c = (L & 7) << 3;
    *reinterpret_cast<short8*>(tp + r * 72 + c) =
        *reinterpret_cast<const short8*>(tpb + (size_t)bh * 4096 + r * 64 + c);
    *reinterpret_cast<short8*>(tn + r * 72 + c) =
        *reinterpret_cast<const short8*>(tnb + (size_t)bh * 4096 + r * 64 + c);
    *reinterpret_cast<short8*>(Vc + r * 72 + c) =
        *reinterpret_cast<const short8*>(vctg + (size_t)bh * 4096 + r * 64 + c);
  }
  for (int L = t; L < 2048; L += 256) {
    const int r = L >> 3, c = (L & 7) << 3;
    *reinterpret_cast<short8*>(Qs + r * 72 + c) =
        *reinterpret_cast<const short8*>(qg + (size_t)bh * 65536 + (size_t)(q0 + r) * 64 + c);
  }
  __syncthreads();
  bf16x4 vcf[4][4];
#pragma unroll
  for (int tile = 0; tile < 4; ++tile)
#pragma unroll
    for (int dt = 0; dt < 4; ++dt)
      vcf[tile][dt] = *reinterpret_cast<const bf16x4*>(Vc + (dt * 16 + l) * 72 + tile * 16 + g * 4);
  const float lam2 = lam2p[0];
  const int b = bh / 12, head = bh % 12;
  float nw[4];
#pragma unroll
  for (int dt = 0; dt < 4; ++dt) nw[dt] = norm2_w[dt * 16 + l];

  for (int s = 0; s < 4; ++s) {
    const int rrow = (w * 4 + s) * 16;       // in-chunk row base of this strip
    short8 qf[2];
#pragma unroll
    for (int h = 0; h < 2; ++h)
      qf[h] = *reinterpret_cast<const short8*>(Qs + (rrow + l) * 72 + h * 32 + g * 8);
    bf16x4 pf[2][4];
#pragma unroll
    for (int pp = 0; pp < 2; ++pp) {
      const unsigned short* tm = pp ? tn : tp;
      f32x4 sv[4];
#pragma unroll
      for (int tile = 0; tile < 4; ++tile) {
        sv[tile] = (f32x4){0.f, 0.f, 0.f, 0.f};
#pragma unroll
        for (int h = 0; h < 2; ++h) {
          const short8 tfb = *reinterpret_cast<const short8*>(tm + (tile * 16 + l) * 72 + h * 32 + g * 8);
          sv[tile] = __builtin_amdgcn_mfma_f32_16x16x32_bf16(tfb, qf[h], sv[tile], 0, 0, 0);
        }
      }
      float p[4][4];
      float lmax = -1e30f;
#pragma unroll
      for (int tile = 0; tile < 4; ++tile)
#pragma unroll
        for (int r = 0; r < 4; ++r) {
          const float v = sv[tile][r] * 0.125f;
          p[tile][r] = v;
          lmax = fmaxf(lmax, v);
        }
      lmax = fmaxf(lmax, __shfl_xor(lmax, 16));
      lmax = fmaxf(lmax, __shfl_xor(lmax, 32));
      float ps = 0.f;
#pragma unroll
      for (int tile = 0; tile < 4; ++tile)
#pragma unroll
        for (int r = 0; r < 4; ++r) {
          const float e = __expf(p[tile][r] - lmax);
          p[tile][r] = e;
          ps += e;
        }
      ps += __shfl_xor(ps, 16);
      ps += __shfl_xor(ps, 32);
      const float inv = 1.f / ps;
#pragma unroll
      for (int tile = 0; tile < 4; ++tile) {
        bf16x4 pk;
        pk[0] = (short)f2bf(p[tile][0] * inv); pk[1] = (short)f2bf(p[tile][1] * inv);
        pk[2] = (short)f2bf(p[tile][2] * inv); pk[3] = (short)f2bf(p[tile][3] * inv);
        pf[pp][tile] = pk;
      }
    }
    f32x4 a1[4], a2[4];
#pragma unroll
    for (int dt = 0; dt < 4; ++dt) {
      a1[dt] = (f32x4){0.f, 0.f, 0.f, 0.f};
      a2[dt] = (f32x4){0.f, 0.f, 0.f, 0.f};
    }
#pragma unroll
    for (int tile = 0; tile < 4; ++tile)
#pragma unroll
      for (int dt = 0; dt < 4; ++dt) {
        a1[dt] = __builtin_amdgcn_mfma_f32_16x16x16bf16_1k(pf[0][tile], vcf[tile][dt], a1[dt], 0, 0, 0);
        a2[dt] = __builtin_amdgcn_mfma_f32_16x16x16bf16_1k(pf[1][tile], vcf[tile][dt], a2[dt], 0, 0, 0);
      }
    float od[4][4], ss[4] = {0.f, 0.f, 0.f, 0.f};
#pragma unroll
    for (int dt = 0; dt < 4; ++dt)
#pragma unroll
      for (int r = 0; r < 4; ++r) {
        const float v = a1[dt][r] - lam2 * a2[dt][r];
        od[dt][r] = v;
        ss[r] += v * v;
      }
#pragma unroll
    for (int r = 0; r < 4; ++r) {
      ss[r] += __shfl_xor(ss[r], 1);
      ss[r] += __shfl_xor(ss[r], 2);
      ss[r] += __shfl_xor(ss[r], 4);
      ss[r] += __shfl_xor(ss[r], 8);
    }
    float sc[4];
#pragma unroll
    for (int r = 0; r < 4; ++r) sc[r] = 0.5f / (sqrtf(ss[r]) * 0.125f + 1e-6f);
    const size_t ob = ((size_t)b * 1024 + q0 + rrow + 4 * g) * 768 + head * 64;
#pragma unroll
    for (int dt = 0; dt < 4; ++dt) {
#pragma unroll
      for (int r = 0; r < 4; ++r)
        opb[ob + (size_t)r * 768 + dt * 16 + l] = f2bf(od[dt][r] * sc[r] * nw[dt]);
    }
  }
}

// ---- K5: proj GEMM, 128x256 tile, 2-phase counted-vmcnt, +bias, f32 out ---
__global__ __launch_bounds__(512, 2) void gemm_proj_kernel(const unsigned short* __restrict__ A,
    const unsigned short* __restrict__ Bm, const float* __restrict__ bias,
    float* __restrict__ out) {
  __shared__ __align__(16) unsigned short sh[49152];   // 96 KiB
  const int t = threadIdx.x;
  const int lane = t & 63;
  const int w = t >> 6;
  const int wm = w >> 2, wn = w & 3;
  const int l = lane & 15, g = lane >> 4;
  const int id = blockIdx.x;                 // nwg = 768 = 8*96
  const int swz = (id & 7) * 96 + (id >> 3);
  const int rt = swz / 3, ct = swz % 3;
  const int row0 = rt * 128, col0 = ct * 256;

  f32x4 acc[4][4];
#pragma unroll
  for (int i = 0; i < 4; ++i)
#pragma unroll
    for (int j = 0; j < 4; ++j) acc[i][j] = (f32x4){0.f, 0.f, 0.f, 0.f};

  stage_ht(A, sh, row0, 0, 0, w, lane);
  stage_ht(Bm, sh + 16384, col0, 0, 0, w, lane);
  stage_ht(Bm, sh + 16384, col0, 0, 128, w, lane);
  stage_ht(Bm, sh + 32768, col0, 64, 0, w, lane);
  stage_ht(Bm, sh + 32768, col0, 64, 128, w, lane);
  wait_vm4();
  bar();

  for (int m = 0; m < 12; ++m) {
    const int d = m & 1;
    const unsigned short* Ab = sh + d * 8192;
    const unsigned short* Bb = sh + 16384 + d * 16384;
    short8 af[4][2], bfv[4][2];
    // p1
#pragma unroll
    for (int mt = 0; mt < 4; ++mt)
#pragma unroll
      for (int kc = 0; kc < 2; ++kc) {
        const int r = wm * 64 + mt * 16 + l;
        af[mt][kc] = *reinterpret_cast<const short8*>(Ab + r * 64 + (((kc << 2) | g) ^ (r & 7)) * 8);
      }
#pragma unroll
    for (int nt = 0; nt < 2; ++nt)
#pragma unroll
      for (int kc = 0; kc < 2; ++kc) {
        const int r = wn * 64 + nt * 16 + l;
        bfv[nt][kc] = *reinterpret_cast<const short8*>(Bb + r * 64 + (((kc << 2) | g) ^ (r & 7)) * 8);
      }
    if (m + 1 < 12) stage_ht(A, sh + (d ^ 1) * 8192, row0, (m + 1) * 64, 0, w, lane);
    bar();
    __builtin_amdgcn_s_setprio(1);
#pragma unroll
    for (int kc = 0; kc < 2; ++kc)
#pragma unroll
      for (int mt = 0; mt < 4; ++mt)
#pragma unroll
        for (int nt = 0; nt < 2; ++nt)
          acc[mt][nt] = __builtin_amdgcn_mfma_f32_16x16x32_bf16(af[mt][kc], bfv[nt][kc], acc[mt][nt], 0, 0, 0);
    __builtin_amdgcn_s_setprio(0);
    bar();
    // p2
#pragma unroll
    for (int nt = 2; nt < 4; ++nt)
#pragma unroll
      for (int kc = 0; kc < 2; ++kc) {
        const int r = wn * 64 + nt * 16 + l;
        bfv[nt][kc] = *reinterpret_cast<const short8*>(Bb + r * 64 + (((kc << 2) | g) ^ (r & 7)) * 8);
      }
    wait_lgkm0();
    bar();
    if (m + 2 < 12) {
      stage_ht(Bm, sh + 16384 + d * 16384, col0, (m + 2) * 64, 0, w, lane);
      stage_ht(Bm, sh + 16384 + d * 16384, col0, (m + 2) * 64, 128, w, lane);
    }
    __builtin_amdgcn_s_setprio(1);
#pragma unroll
    for (int kc = 0; kc < 2; ++kc)
#pragma unroll
      for (int mt = 0; mt < 4; ++mt)
#pragma unroll
        for (int nt = 2; nt < 4; ++nt)
          acc[mt][nt] = __builtin_amdgcn_mfma_f32_16x16x32_bf16(af[mt][kc], bfv[nt][kc], acc[mt][nt], 0, 0, 0);
    __builtin_amdgcn_s_setprio(0);
    if (m < 11) {
      if (m == 10) wait_vm0(); else wait_vm4();
    }
    bar();
  }
#pragma unroll
  for (int ni = 0; ni < 4; ++ni) {
    const int colg = ct * 256 + wn * 64 + ni * 16 + l;
    const float bv = bias[colg];
#pragma unroll
    for (int mi = 0; mi < 4; ++mi)
#pragma unroll
      for (int r = 0; r < 4; ++r) {
        const int row = row0 + wm * 64 + mi * 16 + (g << 2) + r;
        out[(size_t)row * 768 + colg] = acc[mi][ni][r] + bv;
      }
  }
}

// ---------------------------------------------------------------------------
extern "C" void kernel_launch(void* const* d_in, const int* in_sizes, int n_in,
                              void* d_out, int out_size, void* d_ws, size_t ws_size,
                              hipStream_t stream) {
  (void)in_sizes; (void)n_in; (void)out_size; (void)ws_size;
  const float* x       = (const float*)d_in[0];
  const float* Wqkv    = (const float*)d_in[1];
  const float* Wproj   = (const float*)d_in[2];
  const float* bproj   = (const float*)d_in[3];
  const float* Wpos    = (const float*)d_in[4];
  const float* Wneg    = (const float*)d_in[5];
  const float* conv_w  = (const float*)d_in[6];
  const float* lam1    = (const float*)d_in[7];
  const float* lam2    = (const float*)d_in[8];
  const float* norm1_w = (const float*)d_in[9];
  const float* norm2_w = (const float*)d_in[10];
  float* out = (float*)d_out;
  char* ws = (char*)d_ws;
  unsigned short* qb   = (unsigned short*)(ws + OFF_Q);
  unsigned short* kb   = (unsigned short*)(ws + OFF_K);
  unsigned short* vtb  = (unsigned short*)(ws + OFF_VT);
  unsigned short* tpbb = (unsigned short*)(ws + OFF_TPB);
  unsigned short* tnbb = (unsigned short*)(ws + OFF_TNB);
  unsigned short* vctb = (unsigned short*)(ws + OFF_VCT);
  unsigned short* opb  = (unsigned short*)(ws + OFF_OP);
  unsigned short* xb   = (unsigned short*)(ws + OFF_XB);
  unsigned short* wqb  = (unsigned short*)(ws + OFF_WQ);
  unsigned short* wpb  = (unsigned short*)(ws + OFF_WP);
  float* epb           = (float*)(ws + OFF_EP);
  float* enb           = (float*)(ws + OFF_EN);

  cast3_kernel<<<dim3(26880), dim3(256), 0, stream>>>(x, Wqkv, Wproj, xb, wqb, wpb);
  gemm_qkv_kernel<<<dim3(1152), dim3(512), 0, stream>>>(xb, wqb, qb, kb, vtb);
  gq_embed_kernel<<<dim3(384), dim3(256), 0, stream>>>(qb, Wpos, Wneg, epb, enb);
  conv_pool_kernel<<<dim3(384, 4), dim3(256), 0, stream>>>(qb, conv_w, epb, enb, tpbb, tnbb);
  stage1_kernel<<<dim3(384), dim3(256), 0, stream>>>(kb, vtb, tpbb, tnbb, lam1, norm1_w, vctb);
  stage2_kernel<<<dim3(384, 4), dim3(256), 0, stream>>>(qb, tpbb, tnbb, vctb, lam2, norm2_w, opb);
  gemm_proj_kernel<<<dim3(768), dim3(512), 0, stream>>>(opb, wpb, bproj, out);
}

// Round 9
// 387.610 us; speedup vs baseline: 1.0099x; 1.0099x over previous
//
#include <hip/hip_runtime.h>
#include <hip/hip_bf16.h>

// ---------------------------------------------------------------------------
// VisualContrastAttention on MI355X (gfx950)
// B=32, N=1024 (32x32), C=768, heads=12, hd=64, pool 8x8=64 tokens
// Pipeline (5 launches):
//   K0  cast x/Wqkv/Wproj f32->bf16 + zero gqs
//   K1  qkv GEMM: 256x256, 8-wave, 8-phase counted-vmcnt; q-tiles also
//       accumulate row-sums into gqs[bh][d] (f32 atomics)
//   K2  conv3x3+GELU+avgpool; ep/en computed in-block from gqs
//   K3  fused stage-1 + stage-2: flash attn (vct in LDS only) then
//       q-attends-tokens, rmsnorm, out_patch bf16
//   K4  proj GEMM: 128x256, 8-wave, 2-phase counted-vmcnt + bias -> f32
// ---------------------------------------------------------------------------

typedef __attribute__((ext_vector_type(8))) short short8;
typedef __attribute__((ext_vector_type(4))) short bf16x4;
typedef __attribute__((ext_vector_type(4))) float f32x4;

#define DEV static __device__ __forceinline__

DEV unsigned short f2bf(float f) {
  unsigned int b; __builtin_memcpy(&b, &f, 4);
  unsigned int r = (b + 0x7FFFu + ((b >> 16) & 1u)) >> 16;
  return (unsigned short)r;
}
DEV float bf2f(unsigned short u) {
  unsigned int b = ((unsigned int)u) << 16;
  float f; __builtin_memcpy(&f, &b, 4);
  return f;
}

DEV void gload16(const unsigned short* g, unsigned short* l) {
  __builtin_amdgcn_global_load_lds(
      (const __attribute__((address_space(1))) unsigned int*)g,
      (__attribute__((address_space(3))) unsigned int*)l, 16, 0, 0);
}

DEV void bar() {
  asm volatile("" ::: "memory");
  __builtin_amdgcn_s_barrier();
  asm volatile("" ::: "memory");
}
DEV void wait_vm4() { asm volatile("s_waitcnt vmcnt(4)" ::: "memory"); __builtin_amdgcn_sched_barrier(0); }
DEV void wait_vm0() { asm volatile("s_waitcnt vmcnt(0)" ::: "memory"); __builtin_amdgcn_sched_barrier(0); }
DEV void wait_lgkm0() { asm volatile("s_waitcnt lgkmcnt(0)" ::: "memory"); __builtin_amdgcn_sched_barrier(0); }

// ---- workspace layout (bytes) ---------------------------------------------
constexpr size_t SZ_QKV = (size_t)32 * 12 * 1024 * 64 * 2;   // 50331648 bf16
constexpr size_t OFF_Q   = 0;
constexpr size_t OFF_K   = OFF_Q + SZ_QKV;
constexpr size_t OFF_VT  = OFF_K + SZ_QKV;                    // vt[bh][d][n] bf16
constexpr size_t OFF_TPB = OFF_VT + SZ_QKV;                   // bf16 384*64*64
constexpr size_t OFF_TNB = OFF_TPB + 3145728;
constexpr size_t OFF_OP  = OFF_TNB + 3145728;                 // bf16 32768*768
constexpr size_t OFF_XB  = OFF_OP + SZ_QKV;
constexpr size_t OFF_WQ  = OFF_XB + SZ_QKV;
constexpr size_t OFF_WP  = OFF_WQ + 3538944;
constexpr size_t OFF_GQ  = OFF_WP + 1179648;                  // f32 384*64 row-sums

// ---- K0: merged f32 -> bf16 cast + gqs zero -------------------------------
__global__ __launch_bounds__(256) void cast3_kernel(const float* __restrict__ x,
    const float* __restrict__ wq, const float* __restrict__ wp,
    unsigned short* __restrict__ xd, unsigned short* __restrict__ wqd,
    unsigned short* __restrict__ wpd, float* __restrict__ gqs) {
  const int i = blockIdx.x * 256 + threadIdx.x;    // float4 index
  if (i < 24576) gqs[i] = 0.f;
  const float* src; unsigned short* dst; int off;
  if (i < 6291456) { src = x; dst = xd; off = i; }
  else if (i < 6733824) { src = wq; dst = wqd; off = i - 6291456; }
  else { src = wp; dst = wpd; off = i - 6733824; }
  float4 v = reinterpret_cast<const float4*>(src)[off];
  ushort4 o;
  o.x = f2bf(v.x); o.y = f2bf(v.y); o.z = f2bf(v.z); o.w = f2bf(v.w);
  reinterpret_cast<ushort4*>(dst)[off] = o;
}

// stage 128 rows x 64 cols (stride-768 source) with XOR-swizzled source chunks
DEV void stage_ht(const unsigned short* __restrict__ G, unsigned short* shbase,
                  int grow0, int k0, int htrow0, int w, int lane) {
  const int rl = lane >> 3;
  const int ck = (lane & 7) ^ rl;
  const unsigned short* s0 = G + (size_t)(grow0 + htrow0 + w * 16 + rl) * 768 + k0 + ck * 8;
  gload16(s0, shbase + (htrow0 + w * 16) * 64);
  gload16(s0 + (size_t)8 * 768, shbase + (htrow0 + w * 16 + 8) * 64);
}

// ---- K1: qkv GEMM, 256^2 8-phase (+ gq row-sum accumulation) --------------
__global__ __launch_bounds__(512, 2) void gemm_qkv_kernel(const unsigned short* __restrict__ A,
    const unsigned short* __restrict__ Bm, unsigned short* __restrict__ q,
    unsigned short* __restrict__ k, unsigned short* __restrict__ vt,
    float* __restrict__ gqs) {
  __shared__ __align__(16) unsigned short sh[65536];   // 128 KiB
  const int t = threadIdx.x;
  const int lane = t & 63;
  const int w = t >> 6;
  const int wm = w >> 2, wn = w & 3;
  const int l = lane & 15, g = lane >> 4;
  const int id = blockIdx.x;
  const int swz = (id & 7) * 144 + (id >> 3);
  const int rt = swz / 9, ct = swz % 9;
  const int row0 = rt * 256, col0 = ct * 256;

  f32x4 acc[8][4];
#pragma unroll
  for (int i = 0; i < 8; ++i)
#pragma unroll
    for (int j = 0; j < 4; ++j) acc[i][j] = (f32x4){0.f, 0.f, 0.f, 0.f};

  stage_ht(A, sh, row0, 0, 0, w, lane);
  stage_ht(A, sh, row0, 0, 128, w, lane);
  stage_ht(Bm, sh + 32768, col0, 0, 0, w, lane);
  stage_ht(Bm, sh + 32768, col0, 0, 128, w, lane);
  stage_ht(Bm, sh + 32768 + 16384, col0, 64, 0, w, lane);
  stage_ht(Bm, sh + 32768 + 16384, col0, 64, 128, w, lane);
  wait_vm4();
  bar();

  for (int m = 0; m < 12; ++m) {
    const int d = m & 1;
    const unsigned short* Ab = sh + d * 16384;
    const unsigned short* Bb = sh + 32768 + d * 16384;
    short8 af[4][2], bf0[2][2], bf1[2][2];
    // p1
#pragma unroll
    for (int mt = 0; mt < 4; ++mt)
#pragma unroll
      for (int kc = 0; kc < 2; ++kc) {
        const int r = wm * 128 + mt * 16 + l;
        af[mt][kc] = *reinterpret_cast<const short8*>(Ab + r * 64 + (((kc << 2) | g) ^ (r & 7)) * 8);
      }
#pragma unroll
    for (int nt = 0; nt < 2; ++nt)
#pragma unroll
      for (int kc = 0; kc < 2; ++kc) {
        const int r = wn * 64 + nt * 16 + l;
        bf0[nt][kc] = *reinterpret_cast<const short8*>(Bb + r * 64 + (((kc << 2) | g) ^ (r & 7)) * 8);
      }
    if (m + 1 < 12) stage_ht(A, sh + (d ^ 1) * 16384, row0, (m + 1) * 64, 0, w, lane);
    bar();
    __builtin_amdgcn_s_setprio(1);
#pragma unroll
    for (int kc = 0; kc < 2; ++kc)
#pragma unroll
      for (int mt = 0; mt < 4; ++mt)
#pragma unroll
        for (int nt = 0; nt < 2; ++nt)
          acc[mt][nt] = __builtin_amdgcn_mfma_f32_16x16x32_bf16(af[mt][kc], bf0[nt][kc], acc[mt][nt], 0, 0, 0);
    __builtin_amdgcn_s_setprio(0);
    bar();
    // p2
#pragma unroll
    for (int nt = 0; nt < 2; ++nt)
#pragma unroll
      for (int kc = 0; kc < 2; ++kc) {
        const int r = wn * 64 + 32 + nt * 16 + l;
        bf1[nt][kc] = *reinterpret_cast<const short8*>(Bb + r * 64 + (((kc << 2) | g) ^ (r & 7)) * 8);
      }
    if (m + 1 < 12) stage_ht(A, sh + (d ^ 1) * 16384, row0, (m + 1) * 64, 128, w, lane);
    bar();
    __builtin_amdgcn_s_setprio(1);
#pragma unroll
    for (int kc = 0; kc < 2; ++kc)
#pragma unroll
      for (int mt = 0; mt < 4; ++mt)
#pragma unroll
        for (int nt = 0; nt < 2; ++nt)
          acc[mt][2 + nt] = __builtin_amdgcn_mfma_f32_16x16x32_bf16(af[mt][kc], bf1[nt][kc], acc[mt][2 + nt], 0, 0, 0);
    __builtin_amdgcn_s_setprio(0);
    bar();
    // p3
#pragma unroll
    for (int mt = 0; mt < 4; ++mt)
#pragma unroll
      for (int kc = 0; kc < 2; ++kc) {
        const int r = wm * 128 + 64 + mt * 16 + l;
        af[mt][kc] = *reinterpret_cast<const short8*>(Ab + r * 64 + (((kc << 2) | g) ^ (r & 7)) * 8);
      }
    if (m + 2 < 12) stage_ht(Bm, sh + 32768 + d * 16384, col0, (m + 2) * 64, 0, w, lane);
    bar();
    __builtin_amdgcn_s_setprio(1);
#pragma unroll
    for (int kc = 0; kc < 2; ++kc)
#pragma unroll
      for (int mt = 0; mt < 4; ++mt)
#pragma unroll
        for (int nt = 0; nt < 2; ++nt)
          acc[4 + mt][2 + nt] = __builtin_amdgcn_mfma_f32_16x16x32_bf16(af[mt][kc], bf1[nt][kc], acc[4 + mt][2 + nt], 0, 0, 0);
    __builtin_amdgcn_s_setprio(0);
    bar();
    // p4
    if (m + 2 < 12) stage_ht(Bm, sh + 32768 + d * 16384, col0, (m + 2) * 64, 128, w, lane);
    bar();
    __builtin_amdgcn_s_setprio(1);
#pragma unroll
    for (int kc = 0; kc < 2; ++kc)
#pragma unroll
      for (int mt = 0; mt < 4; ++mt)
#pragma unroll
        for (int nt = 0; nt < 2; ++nt)
          acc[4 + mt][nt] = __builtin_amdgcn_mfma_f32_16x16x32_bf16(af[mt][kc], bf0[nt][kc], acc[4 + mt][nt], 0, 0, 0);
    __builtin_amdgcn_s_setprio(0);
    if (m < 11) {
      if (m == 10) wait_vm0(); else wait_vm4();
    }
    bar();
  }

  const int s_ = ct / 3;
  if (s_ == 2) {
#pragma unroll
    for (int ni = 0; ni < 4; ++ni) {
      const int colg = (ct % 3) * 256 + wn * 64 + ni * 16 + l;
      const int head = colg >> 6, dd = colg & 63;
#pragma unroll
      for (int mi = 0; mi < 8; ++mi) {
        const int row = row0 + wm * 128 + mi * 16 + (g << 2);
        const int b = row >> 10, n = row & 1023;
        ushort4 pk;
        pk.x = f2bf(acc[mi][ni][0]); pk.y = f2bf(acc[mi][ni][1]);
        pk.z = f2bf(acc[mi][ni][2]); pk.w = f2bf(acc[mi][ni][3]);
        *reinterpret_cast<ushort4*>(vt + ((((size_t)b * 12 + head) * 64 + dd) << 10) + n) = pk;
      }
    }
  } else {
    unsigned short* dst = (s_ == 0) ? q : k;
#pragma unroll
    for (int ni = 0; ni < 4; ++ni) {
      const int colg = (ct % 3) * 256 + wn * 64 + ni * 16 + l;
      const int head = colg >> 6, dd = colg & 63;
#pragma unroll
      for (int mi = 0; mi < 8; ++mi) {
#pragma unroll
        for (int r = 0; r < 4; ++r) {
          const int row = row0 + wm * 128 + mi * 16 + (g << 2) + r;
          const int b = row >> 10, n = row & 1023;
          dst[(((size_t)b * 12 + head) * 1024 + n) * 64 + dd] = f2bf(acc[mi][ni][r]);
        }
      }
    }
    if (s_ == 0) {
      // gq accumulation: thread partial over its 32 rows, reduce over g, atomic
      const int b = row0 >> 10;                    // 256-row tile within one b
#pragma unroll
      for (int ni = 0; ni < 4; ++ni) {
        const int colg = ct * 256 + wn * 64 + ni * 16 + l;
        const int head = colg >> 6, dd = colg & 63;
        float gs = 0.f;
#pragma unroll
        for (int mi = 0; mi < 8; ++mi)
#pragma unroll
          for (int r = 0; r < 4; ++r) gs += acc[mi][ni][r];
        gs += __shfl_xor(gs, 16);
        gs += __shfl_xor(gs, 32);
        if (g == 0) atomicAdd(&gqs[((size_t)b * 12 + head) * 64 + dd], gs);
      }
    }
  }
}

// ---- K2: conv3x3 depthwise + GELU + 4x4 mean pool (ep/en in-block) --------
__global__ __launch_bounds__(256) void conv_pool_kernel(const unsigned short* __restrict__ qg,
    const float* __restrict__ conv_w, const float* __restrict__ Wpos,
    const float* __restrict__ Wneg, const float* __restrict__ gqs,
    unsigned short* __restrict__ t_pos, unsigned short* __restrict__ t_neg) {
  const int bh = blockIdx.x;
  const int quad = blockIdx.y;
  const unsigned short* qp = qg + (size_t)bh * 65536;
  __shared__ float pool_s[16][64];
  __shared__ float ep_s[64], en_s[64];
  const int t = threadIdx.x;
  // embed preamble: e = (gqs/1024) @ W^T
  if (t < 128) {
    const int d2 = t & 63;
    const float* Wm = (t < 64) ? Wpos : Wneg;
    float e = 0.f;
    for (int dd = 0; dd < 64; ++dd)
      e += gqs[bh * 64 + dd] * (1.0f / 1024.0f) * Wm[d2 * 64 + dd];
    (t < 64 ? ep_s : en_s)[d2] = e;
  }
  const int dg = t & 7, sp = t >> 3;
  const int d0 = dg << 3;
  float cw[3][3][8];
#pragma unroll
  for (int ky = 0; ky < 3; ++ky)
#pragma unroll
    for (int kx = 0; kx < 3; ++kx)
#pragma unroll
      for (int j = 0; j < 8; ++j)
        cw[ky][kx][j] = conv_w[(d0 + j) * 9 + ky * 3 + kx];
#pragma unroll
  for (int pyl = 0; pyl < 2; ++pyl) {
    float win[8] = {0.f, 0.f, 0.f, 0.f, 0.f, 0.f, 0.f, 0.f};
#pragma unroll
    for (int iy = 0; iy < 4; ++iy) {
      const int y = quad * 8 + pyl * 4 + iy;
      float a[8] = {0.f, 0.f, 0.f, 0.f, 0.f, 0.f, 0.f, 0.f};
#pragma unroll
      for (int ky = 0; ky < 3; ++ky) {
        const int yy = y + ky - 1;
        if (yy < 0 || yy > 31) continue;
#pragma unroll
        for (int kx = 0; kx < 3; ++kx) {
          const int xx = sp + kx - 1;
          if (xx < 0 || xx > 31) continue;
          const short8 v = *reinterpret_cast<const short8*>(qp + (size_t)(yy * 32 + xx) * 64 + d0);
#pragma unroll
          for (int j = 0; j < 8; ++j) a[j] += bf2f((unsigned short)v[j]) * cw[ky][kx][j];
        }
      }
#pragma unroll
      for (int j = 0; j < 8; ++j)
        win[j] += 0.5f * a[j] * (1.0f + erff(a[j] * 0.70710678118654752440f));
    }
#pragma unroll
    for (int j = 0; j < 8; ++j) {
      win[j] += __shfl_xor(win[j], 8);
      win[j] += __shfl_xor(win[j], 16);
    }
    if ((sp & 3) == 0) {
      const int px = sp >> 2;
#pragma unroll
      for (int j = 0; j < 8; ++j) pool_s[pyl * 8 + px][d0 + j] = win[j];
    }
  }
  __syncthreads();
#pragma unroll
  for (int i = 0; i < 4; ++i) {
    const int idx = i * 256 + t;
    const int m = idx >> 6, dd = idx & 63;
    const int mg = quad * 16 + m;
    const float base = pool_s[m][dd] * (1.0f / 16.0f);
    t_pos[(size_t)bh * 4096 + mg * 64 + dd] = f2bf(base + ep_s[dd]);
    t_neg[(size_t)bh * 4096 + mg * 64 + dd] = f2bf(base + en_s[dd]);
  }
}

// ---- K3: fused stage-1 + stage-2 ------------------------------------------
// block = bh, 4 waves.  Phase 1: flash attn over 1024 kv -> v_contrast in
// LDS Vc[64][72] (never HBM).  Phase 2: 16 q-strips/wave attend the 64
// contrast tokens, rmsnorm, out_patch bf16.
__global__ __launch_bounds__(256) void stage12_kernel(const unsigned short* __restrict__ kg,
    const unsigned short* __restrict__ vtg, const unsigned short* __restrict__ qg,
    const unsigned short* __restrict__ tpb, const unsigned short* __restrict__ tnb,
    const float* __restrict__ lam1p, const float* __restrict__ norm1_w,
    const float* __restrict__ lam2p, const float* __restrict__ norm2_w,
    unsigned short* __restrict__ opb) {
  const int bh = blockIdx.x;
  __shared__ unsigned short tp[64 * 72], tn[64 * 72], Vc[64 * 72];
  __shared__ __align__(16) unsigned short Ks[2][4096];
  __shared__ __align__(16) unsigned short Vts[2][4096];
  const int t = threadIdx.x;
  const int lane = t & 63;
  const int w = t >> 6;
  const int l = lane & 15, g = lane >> 4;
  const size_t kbase = (size_t)bh * 65536;
  const int rl = lane >> 3, ck = (lane & 7) ^ rl;

  for (int L = t; L < 512; L += 256) {
    const int r = L >> 3, c = (L & 7) << 3;
    *reinterpret_cast<short8*>(tp + r * 72 + c) =
        *reinterpret_cast<const short8*>(tpb + (size_t)bh * 4096 + r * 64 + c);
    *reinterpret_cast<short8*>(tn + r * 72 + c) =
        *reinterpret_cast<const short8*>(tnb + (size_t)bh * 4096 + r * 64 + c);
  }
  auto stageKV = [&](int buf, int n0) {
    const unsigned short* ksrc = kg + kbase + (size_t)(n0 + w * 16 + rl) * 64 + ck * 8;
    gload16(ksrc, &Ks[buf][(w * 16) * 64]);
    gload16(ksrc + (size_t)8 * 64, &Ks[buf][(w * 16 + 8) * 64]);
    const unsigned short* vsrc = vtg + kbase + (size_t)(w * 16 + rl) * 1024 + n0 + ck * 8;
    gload16(vsrc, &Vts[buf][(w * 16) * 64]);
    gload16(vsrc + (size_t)8 * 1024, &Vts[buf][(w * 16 + 8) * 64]);
  };
  stageKV(0, 0);
  __syncthreads();   // drains tp/tn ds_writes + stage vmcnt for all waves

  short8 tf[2][2];
#pragma unroll
  for (int h = 0; h < 2; ++h) {
    tf[0][h] = *reinterpret_cast<const short8*>(tp + (w * 16 + l) * 72 + h * 32 + g * 8);
    tf[1][h] = *reinterpret_cast<const short8*>(tn + (w * 16 + l) * 72 + h * 32 + g * 8);
  }
  float Mo[2] = {-1e30f, -1e30f}, Lo[2] = {0.f, 0.f};
  f32x4 acc[2][4];
#pragma unroll
  for (int pp = 0; pp < 2; ++pp)
#pragma unroll
    for (int dt = 0; dt < 4; ++dt) acc[pp][dt] = (f32x4){0.f, 0.f, 0.f, 0.f};

  for (int it = 0; it < 16; ++it) {
    const int buf = it & 1;
    if (it < 15) stageKV(buf ^ 1, (it + 1) * 64);
    short8 kf[4][2];
#pragma unroll
    for (int tile = 0; tile < 4; ++tile)
#pragma unroll
      for (int h = 0; h < 2; ++h) {
        const int R = tile * 16 + l;
        kf[tile][h] = *reinterpret_cast<const short8*>(&Ks[buf][R * 64 + ((((h << 2) | g)) ^ (l & 7)) * 8]);
      }
    bf16x4 pf[2][4];
#pragma unroll
    for (int pp = 0; pp < 2; ++pp) {
      f32x4 s[4];
#pragma unroll
      for (int tile = 0; tile < 4; ++tile) {
        s[tile] = (f32x4){0.f, 0.f, 0.f, 0.f};
#pragma unroll
        for (int h = 0; h < 2; ++h)
          s[tile] = __builtin_amdgcn_mfma_f32_16x16x32_bf16(kf[tile][h], tf[pp][h], s[tile], 0, 0, 0);
      }
      float p[4][4];
      float tmax = -1e30f;
#pragma unroll
      for (int tile = 0; tile < 4; ++tile)
#pragma unroll
        for (int r = 0; r < 4; ++r) {
          const float v = s[tile][r] * 0.125f;
          p[tile][r] = v;
          tmax = fmaxf(tmax, v);
        }
      tmax = fmaxf(tmax, __shfl_xor(tmax, 16));
      tmax = fmaxf(tmax, __shfl_xor(tmax, 32));
      const float nm = fmaxf(Mo[pp], tmax);
      const float al = __expf(Mo[pp] - nm);
      Mo[pp] = nm;
      float ps = 0.f;
#pragma unroll
      for (int tile = 0; tile < 4; ++tile)
#pragma unroll
        for (int r = 0; r < 4; ++r) {
          const float e = __expf(p[tile][r] - nm);
          p[tile][r] = e;
          ps += e;
        }
      ps += __shfl_xor(ps, 16);
      ps += __shfl_xor(ps, 32);
      Lo[pp] = Lo[pp] * al + ps;
#pragma unroll
      for (int tile = 0; tile < 4; ++tile) {
        bf16x4 pk;
        pk[0] = (short)f2bf(p[tile][0]); pk[1] = (short)f2bf(p[tile][1]);
        pk[2] = (short)f2bf(p[tile][2]); pk[3] = (short)f2bf(p[tile][3]);
        pf[pp][tile] = pk;
      }
      float ar[4];
#pragma unroll
      for (int r = 0; r < 4; ++r) ar[r] = __shfl(al, 4 * g + r);
#pragma unroll
      for (int dt = 0; dt < 4; ++dt)
#pragma unroll
        for (int r = 0; r < 4; ++r) acc[pp][dt][r] *= ar[r];
    }
#pragma unroll
    for (int tile = 0; tile < 4; ++tile)
#pragma unroll
      for (int dt = 0; dt < 4; ++dt) {
        const int R = dt * 16 + l;
        const bf16x4 vf = *reinterpret_cast<const bf16x4*>(
            &Vts[buf][R * 64 + (((2 * tile + (g >> 1)) ^ (l & 7)) * 8) + (g & 1) * 4]);
        acc[0][dt] = __builtin_amdgcn_mfma_f32_16x16x16bf16_1k(pf[0][tile], vf, acc[0][dt], 0, 0, 0);
        acc[1][dt] = __builtin_amdgcn_mfma_f32_16x16x16bf16_1k(pf[1][tile], vf, acc[1][dt], 0, 0, 0);
      }
    __syncthreads();
  }
  // ---- contrast + rmsnorm -> Vc (LDS only) ----
  {
    const float inv0 = 1.f / Lo[0], inv1 = 1.f / Lo[1];
    float i1r[4], i2r[4];
#pragma unroll
    for (int r = 0; r < 4; ++r) {
      i1r[r] = __shfl(inv0, 4 * g + r);
      i2r[r] = __shfl(inv1, 4 * g + r);
    }
    const float lam1 = lam1p[0];
    float od[4][4], ss[4] = {0.f, 0.f, 0.f, 0.f};
#pragma unroll
    for (int dt = 0; dt < 4; ++dt)
#pragma unroll
      for (int r = 0; r < 4; ++r) {
        const float v = acc[0][dt][r] * i1r[r] - lam1 * (acc[1][dt][r] * i2r[r]);
        od[dt][r] = v;
        ss[r] += v * v;
      }
#pragma unroll
    for (int r = 0; r < 4; ++r) {
      ss[r] += __shfl_xor(ss[r], 1);
      ss[r] += __shfl_xor(ss[r], 2);
      ss[r] += __shfl_xor(ss[r], 4);
      ss[r] += __shfl_xor(ss[r], 8);
    }
    float sc[4];
#pragma unroll
    for (int r = 0; r < 4; ++r) sc[r] = 0.5f / (sqrtf(ss[r]) * 0.125f + 1e-6f);
    const int mb = w * 16 + 4 * g;
#pragma unroll
    for (int dt = 0; dt < 4; ++dt) {
      const int dd = dt * 16 + l;
      const float nw = norm1_w[dd];
      ushort4 pk;
      pk.x = f2bf(od[dt][0] * sc[0] * nw);
      pk.y = f2bf(od[dt][1] * sc[1] * nw);
      pk.z = f2bf(od[dt][2] * sc[2] * nw);
      pk.w = f2bf(od[dt][3] * sc[3] * nw);
      *reinterpret_cast<ushort4*>(Vc + dd * 72 + mb) = pk;   // Vc[d][m]
    }
  }
  __syncthreads();

  // ---- phase 2: q attends to contrast tokens ----
  bf16x4 vcf[4][4];
#pragma unroll
  for (int tile = 0; tile < 4; ++tile)
#pragma unroll
    for (int dt = 0; dt < 4; ++dt)
      vcf[tile][dt] = *reinterpret_cast<const bf16x4*>(Vc + (dt * 16 + l) * 72 + tile * 16 + g * 4);
  const float lam2 = lam2p[0];
  const int b = bh / 12, head = bh % 12;
  float nw2[4];
#pragma unroll
  for (int dt = 0; dt < 4; ++dt) nw2[dt] = norm2_w[dt * 16 + l];
  const unsigned short* qrow = qg + kbase;

  short8 qf0 = *reinterpret_cast<const short8*>(qrow + (size_t)(w * 256 + l) * 64 + g * 8);
  short8 qf1 = *reinterpret_cast<const short8*>(qrow + (size_t)(w * 256 + l) * 64 + 32 + g * 8);
  for (int s = 0; s < 16; ++s) {
    const int rbase = w * 256 + s * 16;            // wave w owns rows w*256..+255
    short8 qn0, qn1;
    if (s < 15) {
      qn0 = *reinterpret_cast<const short8*>(qrow + (size_t)(rbase + 16 + l) * 64 + g * 8);
      qn1 = *reinterpret_cast<const short8*>(qrow + (size_t)(rbase + 16 + l) * 64 + 32 + g * 8);
    }
    bf16x4 pf[2][4];
#pragma unroll
    for (int pp = 0; pp < 2; ++pp) {
      const unsigned short* tm = pp ? tn : tp;
      f32x4 sv[4];
#pragma unroll
      for (int tile = 0; tile < 4; ++tile) {
        sv[tile] = (f32x4){0.f, 0.f, 0.f, 0.f};
        const short8 tfb0 = *reinterpret_cast<const short8*>(tm + (tile * 16 + l) * 72 + g * 8);
        const short8 tfb1 = *reinterpret_cast<const short8*>(tm + (tile * 16 + l) * 72 + 32 + g * 8);
        sv[tile] = __builtin_amdgcn_mfma_f32_16x16x32_bf16(tfb0, qf0, sv[tile], 0, 0, 0);
        sv[tile] = __builtin_amdgcn_mfma_f32_16x16x32_bf16(tfb1, qf1, sv[tile], 0, 0, 0);
      }
      float p[4][4];
      float lmax = -1e30f;
#pragma unroll
      for (int tile = 0; tile < 4; ++tile)
#pragma unroll
        for (int r = 0; r < 4; ++r) {
          const float v = sv[tile][r] * 0.125f;
          p[tile][r] = v;
          lmax = fmaxf(lmax, v);
        }
      lmax = fmaxf(lmax, __shfl_xor(lmax, 16));
      lmax = fmaxf(lmax, __shfl_xor(lmax, 32));
      float ps = 0.f;
#pragma unroll
      for (int tile = 0; tile < 4; ++tile)
#pragma unroll
        for (int r = 0; r < 4; ++r) {
          const float e = __expf(p[tile][r] - lmax);
          p[tile][r] = e;
          ps += e;
        }
      ps += __shfl_xor(ps, 16);
      ps += __shfl_xor(ps, 32);
      const float inv = 1.f / ps;
#pragma unroll
      for (int tile = 0; tile < 4; ++tile) {
        bf16x4 pk;
        pk[0] = (short)f2bf(p[tile][0] * inv); pk[1] = (short)f2bf(p[tile][1] * inv);
        pk[2] = (short)f2bf(p[tile][2] * inv); pk[3] = (short)f2bf(p[tile][3] * inv);
        pf[pp][tile] = pk;
      }
    }
    f32x4 a1[4], a2[4];
#pragma unroll
    for (int dt = 0; dt < 4; ++dt) {
      a1[dt] = (f32x4){0.f, 0.f, 0.f, 0.f};
      a2[dt] = (f32x4){0.f, 0.f, 0.f, 0.f};
    }
#pragma unroll
    for (int tile = 0; tile < 4; ++tile)
#pragma unroll
      for (int dt = 0; dt < 4; ++dt) {
        a1[dt] = __builtin_amdgcn_mfma_f32_16x16x16bf16_1k(pf[0][tile], vcf[tile][dt], a1[dt], 0, 0, 0);
        a2[dt] = __builtin_amdgcn_mfma_f32_16x16x16bf16_1k(pf[1][tile], vcf[tile][dt], a2[dt], 0, 0, 0);
      }
    float od[4][4], ss[4] = {0.f, 0.f, 0.f, 0.f};
#pragma unroll
    for (int dt = 0; dt < 4; ++dt)
#pragma unroll
      for (int r = 0; r < 4; ++r) {
        const float v = a1[dt][r] - lam2 * a2[dt][r];
        od[dt][r] = v;
        ss[r] += v * v;
      }
#pragma unroll
    for (int r = 0; r < 4; ++r) {
      ss[r] += __shfl_xor(ss[r], 1);
      ss[r] += __shfl_xor(ss[r], 2);
      ss[r] += __shfl_xor(ss[r], 4);
      ss[r] += __shfl_xor(ss[r], 8);
    }
    float sc[4];
#pragma unroll
    for (int r = 0; r < 4; ++r) sc[r] = 0.5f / (sqrtf(ss[r]) * 0.125f + 1e-6f);
    const size_t ob = ((size_t)b * 1024 + rbase + 4 * g) * 768 + head * 64;
#pragma unroll
    for (int dt = 0; dt < 4; ++dt) {
#pragma unroll
      for (int r = 0; r < 4; ++r)
        opb[ob + (size_t)r * 768 + dt * 16 + l] = f2bf(od[dt][r] * sc[r] * nw2[dt]);
    }
    if (s < 15) { qf0 = qn0; qf1 = qn1; }
  }
}

// ---- K4: proj GEMM, 128x256 tile, 2-phase counted-vmcnt, +bias, f32 out ---
__global__ __launch_bounds__(512, 2) void gemm_proj_kernel(const unsigned short* __restrict__ A,
    const unsigned short* __restrict__ Bm, const float* __restrict__ bias,
    float* __restrict__ out) {
  __shared__ __align__(16) unsigned short sh[49152];   // 96 KiB
  const int t = threadIdx.x;
  const int lane = t & 63;
  const int w = t >> 6;
  const int wm = w >> 2, wn = w & 3;
  const int l = lane & 15, g = lane >> 4;
  const int id = blockIdx.x;                 // nwg = 768 = 8*96
  const int swz = (id & 7) * 96 + (id >> 3);
  const int rt = swz / 3, ct = swz % 3;
  const int row0 = rt * 128, col0 = ct * 256;

  f32x4 acc[4][4];
#pragma unroll
  for (int i = 0; i < 4; ++i)
#pragma unroll
    for (int j = 0; j < 4; ++j) acc[i][j] = (f32x4){0.f, 0.f, 0.f, 0.f};

  stage_ht(A, sh, row0, 0, 0, w, lane);
  stage_ht(Bm, sh + 16384, col0, 0, 0, w, lane);
  stage_ht(Bm, sh + 16384, col0, 0, 128, w, lane);
  stage_ht(Bm, sh + 32768, col0, 64, 0, w, lane);
  stage_ht(Bm, sh + 32768, col0, 64, 128, w, lane);
  wait_vm4();
  bar();

  for (int m = 0; m < 12; ++m) {
    const int d = m & 1;
    const unsigned short* Ab = sh + d * 8192;
    const unsigned short* Bb = sh + 16384 + d * 16384;
    short8 af[4][2], bfv[4][2];
    // p1
#pragma unroll
    for (int mt = 0; mt < 4; ++mt)
#pragma unroll
      for (int kc = 0; kc < 2; ++kc) {
        const int r = wm * 64 + mt * 16 + l;
        af[mt][kc] = *reinterpret_cast<const short8*>(Ab + r * 64 + (((kc << 2) | g) ^ (r & 7)) * 8);
      }
#pragma unroll
    for (int nt = 0; nt < 2; ++nt)
#pragma unroll
      for (int kc = 0; kc < 2; ++kc) {
        const int r = wn * 64 + nt * 16 + l;
        bfv[nt][kc] = *reinterpret_cast<const short8*>(Bb + r * 64 + (((kc << 2) | g) ^ (r & 7)) * 8);
      }
    if (m + 1 < 12) stage_ht(A, sh + (d ^ 1) * 8192, row0, (m + 1) * 64, 0, w, lane);
    bar();
    __builtin_amdgcn_s_setprio(1);
#pragma unroll
    for (int kc = 0; kc < 2; ++kc)
#pragma unroll
      for (int mt = 0; mt < 4; ++mt)
#pragma unroll
        for (int nt = 0; nt < 2; ++nt)
          acc[mt][nt] = __builtin_amdgcn_mfma_f32_16x16x32_bf16(af[mt][kc], bfv[nt][kc], acc[mt][nt], 0, 0, 0);
    __builtin_amdgcn_s_setprio(0);
    bar();
    // p2
#pragma unroll
    for (int nt = 2; nt < 4; ++nt)
#pragma unroll
      for (int kc = 0; kc < 2; ++kc) {
        const int r = wn * 64 + nt * 16 + l;
        bfv[nt][kc] = *reinterpret_cast<const short8*>(Bb + r * 64 + (((kc << 2) | g) ^ (r & 7)) * 8);
      }
    wait_lgkm0();
    bar();
    if (m + 2 < 12) {
      stage_ht(Bm, sh + 16384 + d * 16384, col0, (m + 2) * 64, 0, w, lane);
      stage_ht(Bm, sh + 16384 + d * 16384, col0, (m + 2) * 64, 128, w, lane);
    }
    __builtin_amdgcn_s_setprio(1);
#pragma unroll
    for (int kc = 0; kc < 2; ++kc)
#pragma unroll
      for (int mt = 0; mt < 4; ++mt)
#pragma unroll
        for (int nt = 2; nt < 4; ++nt)
          acc[mt][nt] = __builtin_amdgcn_mfma_f32_16x16x32_bf16(af[mt][kc], bfv[nt][kc], acc[mt][nt], 0, 0, 0);
    __builtin_amdgcn_s_setprio(0);
    if (m < 11) {
      if (m == 10) wait_vm0(); else wait_vm4();
    }
    bar();
  }
#pragma unroll
  for (int ni = 0; ni < 4; ++ni) {
    const int colg = ct * 256 + wn * 64 + ni * 16 + l;
    const float bv = bias[colg];
#pragma unroll
    for (int mi = 0; mi < 4; ++mi)
#pragma unroll
      for (int r = 0; r < 4; ++r) {
        const int row = row0 + wm * 64 + mi * 16 + (g << 2) + r;
        out[(size_t)row * 768 + colg] = acc[mi][ni][r] + bv;
      }
  }
}

// ---------------------------------------------------------------------------
extern "C" void kernel_launch(void* const* d_in, const int* in_sizes, int n_in,
                              void* d_out, int out_size, void* d_ws, size_t ws_size,
                              hipStream_t stream) {
  (void)in_sizes; (void)n_in; (void)out_size; (void)ws_size;
  const float* x       = (const float*)d_in[0];
  const float* Wqkv    = (const float*)d_in[1];
  const float* Wproj   = (const float*)d_in[2];
  const float* bproj   = (const float*)d_in[3];
  const float* Wpos    = (const float*)d_in[4];
  const float* Wneg    = (const float*)d_in[5];
  const float* conv_w  = (const float*)d_in[6];
  const float* lam1    = (const float*)d_in[7];
  const float* lam2    = (const float*)d_in[8];
  const float* norm1_w = (const float*)d_in[9];
  const float* norm2_w = (const float*)d_in[10];
  float* out = (float*)d_out;
  char* ws = (char*)d_ws;
  unsigned short* qb   = (unsigned short*)(ws + OFF_Q);
  unsigned short* kb   = (unsigned short*)(ws + OFF_K);
  unsigned short* vtb  = (unsigned short*)(ws + OFF_VT);
  unsigned short* tpbb = (unsigned short*)(ws + OFF_TPB);
  unsigned short* tnbb = (unsigned short*)(ws + OFF_TNB);
  unsigned short* opb  = (unsigned short*)(ws + OFF_OP);
  unsigned short* xb   = (unsigned short*)(ws + OFF_XB);
  unsigned short* wqb  = (unsigned short*)(ws + OFF_WQ);
  unsigned short* wpb  = (unsigned short*)(ws + OFF_WP);
  float* gqsb          = (float*)(ws + OFF_GQ);

  cast3_kernel<<<dim3(26880), dim3(256), 0, stream>>>(x, Wqkv, Wproj, xb, wqb, wpb, gqsb);
  gemm_qkv_kernel<<<dim3(1152), dim3(512), 0, stream>>>(xb, wqb, qb, kb, vtb, gqsb);
  conv_pool_kernel<<<dim3(384, 4), dim3(256), 0, stream>>>(qb, conv_w, Wpos, Wneg, gqsb, tpbb, tnbb);
  stage12_kernel<<<dim3(384), dim3(256), 0, stream>>>(kb, vtb, qb, tpbb, tnbb, lam1, norm1_w, lam2, norm2_w, opb);
  gemm_proj_kernel<<<dim3(768), dim3(512), 0, stream>>>(opb, wpb, bproj, out);
}